// Round 7
// baseline (110.388 us; speedup 1.0000x reference)
//
#include <hip/hip_runtime.h>

typedef unsigned int uint;
typedef _Float16 half2v __attribute__((ext_vector_type(2)));
typedef _Float16 half8  __attribute__((ext_vector_type(8)));
typedef float    f32x4  __attribute__((ext_vector_type(4)));

#define BATCH   8192
#define DIM     128
#define NCLS    512
#define TMARGIN 0.3f
#define BIGF    3.402823466e+38f
#define MAXM    128
#define NPAN    64
#define NSLOT   64

// ---------- k_prep: norms + f16 hi/lo split + class scatter ------------------
__global__ __launch_bounds__(256) void k_prep(
    const float* __restrict__ emb, const int* __restrict__ labels,
    _Float16* __restrict__ eh, _Float16* __restrict__ el,
    float* __restrict__ norms, int* __restrict__ counts, int* __restrict__ members) {
  int w = threadIdx.x >> 6, lane = threadIdx.x & 63;
  int row = blockIdx.x * 4 + w;
  float2 v = reinterpret_cast<const float2*>(emb + (size_t)row * DIM)[lane];
  _Float16 h0 = (_Float16)v.x, h1 = (_Float16)v.y;
  half2v hv = {h0, h1};
  half2v lv = {(_Float16)(v.x - (float)h0), (_Float16)(v.y - (float)h1)};
  reinterpret_cast<half2v*>(eh + (size_t)row * DIM)[lane] = hv;
  reinterpret_cast<half2v*>(el + (size_t)row * DIM)[lane] = lv;
  float s = v.x * v.x + v.y * v.y;
  #pragma unroll
  for (int off = 32; off; off >>= 1) s += __shfl_xor(s, off);
  if (lane == 0) {
    norms[row] = s;
    int c = labels[row];
    int p = atomicAdd(&counts[c], 1);
    if (p < MAXM) members[c * MAXM + p] = row;
  }
}

// ---------- k_hp: hardest positive per row (squared -> sqrt) -----------------
__global__ __launch_bounds__(256) void k_hp(
    const float* __restrict__ emb, const float* __restrict__ norms,
    const int* __restrict__ counts, const int* __restrict__ members,
    float* __restrict__ hp) {
  int c = blockIdx.x;
  int m = counts[c]; if (m > MAXM) m = MAXM;
  int w = threadIdx.x >> 6, lane = threadIdx.x & 63;
  int g = lane >> 4, gl = lane & 15;
  for (int a = w; a < m; a += 4) {
    int i = members[c * MAXM + a];
    const float4* pi = reinterpret_cast<const float4*>(emb + (size_t)i * DIM + gl * 8);
    float4 xi0 = pi[0], xi1 = pi[1];
    float ni = norms[i];
    float best = 0.f;
    for (int b = g; b < m; b += 4) {
      if (b == a) continue;
      int j = members[c * MAXM + b];
      const float4* pj = reinterpret_cast<const float4*>(emb + (size_t)j * DIM + gl * 8);
      float4 xj0 = pj[0], xj1 = pj[1];
      float d = xi0.x*xj0.x + xi0.y*xj0.y + xi0.z*xj0.z + xi0.w*xj0.w
              + xi1.x*xj1.x + xi1.y*xj1.y + xi1.z*xj1.z + xi1.w*xj1.w;
      #pragma unroll
      for (int off = 1; off < 16; off <<= 1) d += __shfl_xor(d, off);
      float sq = fmaxf(ni + norms[j] - 2.f * d, 0.f);
      best = fmaxf(best, sq);
    }
    best = fmaxf(best, __shfl_xor(best, 16));
    best = fmaxf(best, __shfl_xor(best, 32));
    if (lane == 0) hp[i] = best > 0.f ? sqrtf(best) : 0.f;
  }
}

// ---------- k_main: symmetric-triangle 128x128 tile, row+col passes ----------
// block (pi,pj), pj>=pi. A = panel pi rows (regs, full K); B = panel pj cols
// staged in K-quarters (16KB, dbuf, kg-major layout, conflict-free ds_read).
// Row-pass: t = 2dot - nj, running max -> rowres[row of pi][slot pj].
// Col-pass (pi!=pj): t_col = 2dot - ni -> rowres[col of pj][slot pi].
__global__ __launch_bounds__(256, 2) void k_main(
    const _Float16* __restrict__ eh, const _Float16* __restrict__ el,
    const int* __restrict__ labels, const float* __restrict__ norms,
    const float* __restrict__ hp, float* __restrict__ rowres) {
  int idx = blockIdx.x;
  int bx = (int)((sqrtf(8.0f * (float)idx + 1.0f) - 1.0f) * 0.5f);
  while ((bx + 1) * (bx + 2) / 2 <= idx) ++bx;
  while (bx * (bx + 1) / 2 > idx) --bx;
  const int pi = idx - bx * (bx + 1) / 2;   // row panel
  const int pj = bx;                        // col panel (pj >= pi)
  const int i0 = pi * 128, j0 = pj * 128;

  __shared__ __align__(16) char lds[32768];
  const int t = threadIdx.x, lane = t & 63, w = t >> 6;
  const int r16 = lane & 15, kg = lane >> 4;

  // stage one K-quarter (k = kq*32..+32) of B panel (h+l, 16KB) into buf C.
  // LDS 16B-unit layout: hl*512 + kslot*128 + col ; linear dest, per-lane src.
  #define STAGE(KQ, C)                                                        \
    {                                                                         \
      _Pragma("unroll") for (int it = 0; it < 4; ++it) {                      \
        const _Float16* sb = (it < 2) ? eh : el;                              \
        int kslot = (it * 2 + (t >> 7)) & 3;                                  \
        const _Float16* gp = sb + (size_t)(j0 + (t & 127)) * DIM              \
                             + (KQ) * 32 + kslot * 8;                         \
        char* lp = lds + (C) * 16384 + it * 4096 + (t >> 6) * 1024;           \
        __builtin_amdgcn_global_load_lds(                                     \
            (const __attribute__((address_space(1))) void*)gp,                \
            (__attribute__((address_space(3))) void*)lp, 16, 0, 0);           \
      }                                                                       \
    }

  // A fragments: rows i0 + 32w + 16m + r16, full K in quarters
  half8 ah[2][4], al[2][4];
  #pragma unroll
  for (int m = 0; m < 2; ++m) {
    size_t rbase = (size_t)(i0 + 32 * w + 16 * m + r16) * DIM + kg * 8;
    #pragma unroll
    for (int ks = 0; ks < 4; ++ks) {
      ah[m][ks] = *reinterpret_cast<const half8*>(eh + rbase + ks * 32);
      al[m][ks] = *reinterpret_cast<const half8*>(el + rbase + ks * 32);
    }
  }

  // row constants
  float ni_[2][4], c2[2][4], rmax[2][4], smax[2][4];
  int li[2][4];
  #pragma unroll
  for (int m = 0; m < 2; ++m)
    #pragma unroll
    for (int q = 0; q < 4; ++q) {
      int gi = i0 + 32 * w + 16 * m + 4 * kg + q;
      float nv = norms[gi], h = hp[gi];
      ni_[m][q] = nv;
      c2[m][q]  = nv - h * h;
      li[m][q]  = labels[gi];
      rmax[m][q] = -BIGF;
      smax[m][q] = -BIGF;
    }
  // col constants
  float njv[8], c2j[8];
  int ljv[8];
  #pragma unroll
  for (int n = 0; n < 8; ++n) {
    int gj = j0 + 16 * n + r16;
    float nv = norms[gj], hj = hp[gj];
    njv[n] = nv;
    c2j[n] = nv - hj * hj;
    ljv[n] = labels[gj];
  }

  f32x4 acc[2][8];
  #pragma unroll
  for (int m = 0; m < 2; ++m)
    #pragma unroll
    for (int n = 0; n < 8; ++n) acc[m][n] = (f32x4){0.f, 0.f, 0.f, 0.f};

  STAGE(0, 0);
  __syncthreads();
  #pragma unroll
  for (int kq = 0; kq < 4; ++kq) {
    if (kq < 3) STAGE(kq + 1, (kq + 1) & 1);
    __builtin_amdgcn_s_setprio(1);
    #pragma unroll
    for (int n = 0; n < 8; ++n) {
      const char* pb = lds + (kq & 1) * 16384 + kg * 2048 + (16 * n + r16) * 16;
      half8 bh = *reinterpret_cast<const half8*>(pb);
      half8 bl = *reinterpret_cast<const half8*>(pb + 8192);
      #pragma unroll
      for (int m = 0; m < 2; ++m) {
        acc[m][n] = __builtin_amdgcn_mfma_f32_16x16x32_f16(ah[m][kq], bh, acc[m][n], 0, 0, 0);
        acc[m][n] = __builtin_amdgcn_mfma_f32_16x16x32_f16(al[m][kq], bh, acc[m][n], 0, 0, 0);
        acc[m][n] = __builtin_amdgcn_mfma_f32_16x16x32_f16(ah[m][kq], bl, acc[m][n], 0, 0, 0);
      }
    }
    __builtin_amdgcn_s_setprio(0);
    if (kq < 3) __syncthreads();
  }
  #undef STAGE

  // ---- epilogue: row + col masked running max in t-space ----
  // C/D layout: col = r16, row = 4*kg + reg(q)
  float crmax[8], csmax[8];
  #pragma unroll
  for (int n = 0; n < 8; ++n) { crmax[n] = -BIGF; csmax[n] = -BIGF; }
  #pragma unroll
  for (int m = 0; m < 2; ++m)
    #pragma unroll
    for (int q = 0; q < 4; ++q)
      #pragma unroll
      for (int n = 0; n < 8; ++n) {
        float d2 = acc[m][n][q] + acc[m][n][q];
        bool diff = (li[m][q] != ljv[n]);
        float tr = d2 - njv[n];
        float trm = diff ? tr : -BIGF;
        rmax[m][q] = fmaxf(rmax[m][q], trm);
        smax[m][q] = fmaxf(smax[m][q], (trm < c2[m][q]) ? trm : -BIGF);
        float tc = d2 - ni_[m][q];
        float tcm = diff ? tc : -BIGF;
        crmax[n] = fmaxf(crmax[n], tcm);
        csmax[n] = fmaxf(csmax[n], (tcm < c2j[n]) ? tcm : -BIGF);
      }

  float2* pp = reinterpret_cast<float2*>(rowres);
  // row pass: reduce over the 16 col-lanes (r16), write slot pj
  #pragma unroll
  for (int m = 0; m < 2; ++m)
    #pragma unroll
    for (int q = 0; q < 4; ++q) {
      float r = rmax[m][q], s = smax[m][q];
      #pragma unroll
      for (int off = 1; off < 16; off <<= 1) {
        r = fmaxf(r, __shfl_xor(r, off));
        s = fmaxf(s, __shfl_xor(s, off));
      }
      if (r16 == 0) {
        int gi = i0 + 32 * w + 16 * m + 4 * kg + q;
        pp[(size_t)gi * NSLOT + pj] = make_float2(r, s);
      }
    }
  // col pass: reduce over kg lanes, write slot pi (skip diagonal)
  if (pi != pj) {
    #pragma unroll
    for (int n = 0; n < 8; ++n) {
      float r = crmax[n], s = csmax[n];
      r = fmaxf(r, __shfl_xor(r, 16));
      s = fmaxf(s, __shfl_xor(s, 16));
      r = fmaxf(r, __shfl_xor(r, 32));
      s = fmaxf(s, __shfl_xor(s, 32));
      if (kg == 0) {
        int gj = j0 + 16 * n + r16;
        // NOTE: each wave covers only rows 32w..32w+31 of pi, so 4 waves
        // produce 4 partial col-maxes; combine via per-wave slot then max in
        // k_red would need 4 slots. Instead: stagger slots by wave and let
        // k_red's 64-slot max absorb it -- but slots are unique per block.
        // Resolve: reduce across waves through LDS (reuse staging buffer).
        reinterpret_cast<float2*>(lds)[(w * 8 + n) * 16 + r16] = make_float2(r, s);
      }
    }
    __syncthreads();
    // wave 0 merges the 4 per-wave col partials and writes
    if (w == 0) {
      #pragma unroll
      for (int n = 0; n < 8; ++n) {
        if (kg == 0) {
          float2 v0 = reinterpret_cast<float2*>(lds)[(0 * 8 + n) * 16 + r16];
          float2 v1 = reinterpret_cast<float2*>(lds)[(1 * 8 + n) * 16 + r16];
          float2 v2 = reinterpret_cast<float2*>(lds)[(2 * 8 + n) * 16 + r16];
          float2 v3 = reinterpret_cast<float2*>(lds)[(3 * 8 + n) * 16 + r16];
          float r = fmaxf(fmaxf(v0.x, v1.x), fmaxf(v2.x, v3.x));
          float s = fmaxf(fmaxf(v0.y, v1.y), fmaxf(v2.y, v3.y));
          int gj = j0 + 16 * n + r16;
          pp[(size_t)gj * NSLOT + pi] = make_float2(r, s);
        }
      }
    }
  }
}

// ---------- k_red: per-row combine of 64 slots -> per-block partial ----------
__global__ __launch_bounds__(256) void k_red(
    const float* __restrict__ norms, const float* __restrict__ hp,
    const float* __restrict__ rowres, float* __restrict__ partial) {
  int gt = blockIdx.x * 256 + threadIdx.x;   // 32768 threads, 4 per row
  int row = gt >> 2, q = gt & 3;
  const float2* pp = reinterpret_cast<const float2*>(rowres) + (size_t)row * NSLOT + q * 16;
  float rmax = -BIGF, smax = -BIGF;
  #pragma unroll
  for (int s = 0; s < 16; ++s) {
    float2 v = pp[s];
    rmax = fmaxf(rmax, v.x);
    smax = fmaxf(smax, v.y);
  }
  rmax = fmaxf(rmax, __shfl_xor(rmax, 1));
  smax = fmaxf(smax, __shfl_xor(smax, 1));
  rmax = fmaxf(rmax, __shfl_xor(rmax, 2));
  smax = fmaxf(smax, __shfl_xor(smax, 2));
  float total = 0.f, count = 0.f;
  if (q == 0) {
    float ni = norms[row], h = hp[row];
    float c1 = ni - (h + TMARGIN) * (h + TMARGIN);
    bool has_neg = rmax > -1e37f;
    float neg_sq  = fmaxf(ni - rmax, 0.f);
    float semi_sq = (smax > c1) ? fmaxf(ni - smax, 0.f) : neg_sq;
    if (h > 0.f && has_neg) {
      total = fmaxf(h - sqrtf(semi_sq) + TMARGIN, 0.f);
      count = 1.f;
    }
  }
  #pragma unroll
  for (int off = 32; off; off >>= 1) {
    total += __shfl_xor(total, off);
    count += __shfl_xor(count, off);
  }
  __shared__ float st[4], sc[4];
  int w = threadIdx.x >> 6, lane = threadIdx.x & 63;
  if (lane == 0) { st[w] = total; sc[w] = count; }
  __syncthreads();
  if (threadIdx.x == 0) {
    float2* po = reinterpret_cast<float2*>(partial);
    po[blockIdx.x] = make_float2(st[0] + st[1] + st[2] + st[3],
                                 sc[0] + sc[1] + sc[2] + sc[3]);
  }
}

// ---------- k_out: final scalar ----------------------------------------------
__global__ void k_out(const float* __restrict__ partial, float* __restrict__ out) {
  const float2* pp = reinterpret_cast<const float2*>(partial);
  int lane = threadIdx.x;
  float2 a = pp[lane], b = pp[lane + 64];
  float T = a.x + b.x, C = a.y + b.y;
  #pragma unroll
  for (int off = 32; off; off >>= 1) {
    T += __shfl_xor(T, off);
    C += __shfl_xor(C, off);
  }
  if (lane == 0) out[0] = C > 0.f ? T / C : 0.f;
}

extern "C" void kernel_launch(void* const* d_in, const int* in_sizes, int n_in,
                              void* d_out, int out_size, void* d_ws, size_t ws_size,
                              hipStream_t stream) {
  const float* emb  = (const float*)d_in[0];
  const int* labels = (const int*)d_in[1];
  float* out        = (float*)d_out;

  _Float16* eh  = (_Float16*)d_ws;                     // 2 MB
  _Float16* el  = eh + (size_t)BATCH * DIM;            // 2 MB
  float* norms  = (float*)(el + (size_t)BATCH * DIM);  // 32 KB
  float* hp     = norms + BATCH;                       // 32 KB
  int* counts   = (int*)(hp + BATCH);                  // 2 KB
  int* members  = counts + NCLS;                       // 256 KB
  float* rowres = (float*)(members + NCLS * MAXM);     // 4 MB
  float* partial = rowres + (size_t)BATCH * NSLOT * 2; // 1 KB

  hipMemsetAsync(counts, 0, NCLS * sizeof(int), stream);
  k_prep<<<BATCH / 4, 256, 0, stream>>>(emb, labels, eh, el, norms, counts, members);
  k_hp<<<NCLS, 256, 0, stream>>>(emb, norms, counts, members, hp);
  const int ntri = NPAN * (NPAN + 1) / 2;   // 2080
  k_main<<<ntri, 256, 0, stream>>>(eh, el, labels, norms, hp, rowres);
  k_red<<<BATCH * 4 / 256, 256, 0, stream>>>(norms, hp, rowres, partial);
  k_out<<<1, 64, 0, stream>>>(partial, out);
}

// Round 8
// 110.150 us; speedup vs baseline: 1.0022x; 1.0022x over previous
//
#include <hip/hip_runtime.h>

typedef unsigned int uint;
typedef _Float16 half2v __attribute__((ext_vector_type(2)));
typedef _Float16 half8  __attribute__((ext_vector_type(8)));
typedef float    f32x4  __attribute__((ext_vector_type(4)));

#define BATCH   8192
#define DIM     128
#define NCLS    512
#define TMARGIN 0.3f
#define BIGF    3.402823466e+38f
#define MAXM    128
#define NPAN    64
#define NSLOT   64

// ---------- k_prep: norms + f16 hi/lo split + class scatter ------------------
__global__ __launch_bounds__(256) void k_prep(
    const float* __restrict__ emb, const int* __restrict__ labels,
    _Float16* __restrict__ eh, _Float16* __restrict__ el,
    float* __restrict__ norms, int* __restrict__ counts, int* __restrict__ members) {
  int w = threadIdx.x >> 6, lane = threadIdx.x & 63;
  int row = blockIdx.x * 4 + w;
  float2 v = reinterpret_cast<const float2*>(emb + (size_t)row * DIM)[lane];
  _Float16 h0 = (_Float16)v.x, h1 = (_Float16)v.y;
  half2v hv = {h0, h1};
  half2v lv = {(_Float16)(v.x - (float)h0), (_Float16)(v.y - (float)h1)};
  reinterpret_cast<half2v*>(eh + (size_t)row * DIM)[lane] = hv;
  reinterpret_cast<half2v*>(el + (size_t)row * DIM)[lane] = lv;
  float s = v.x * v.x + v.y * v.y;
  #pragma unroll
  for (int off = 32; off; off >>= 1) s += __shfl_xor(s, off);
  if (lane == 0) {
    norms[row] = s;
    int c = labels[row];
    int p = atomicAdd(&counts[c], 1);
    if (p < MAXM) members[c * MAXM + p] = row;
  }
}

// ---------- k_hp: hardest positive per row (squared -> sqrt) -----------------
__global__ __launch_bounds__(256) void k_hp(
    const float* __restrict__ emb, const float* __restrict__ norms,
    const int* __restrict__ counts, const int* __restrict__ members,
    float* __restrict__ hp) {
  int c = blockIdx.x;
  int m = counts[c]; if (m > MAXM) m = MAXM;
  int w = threadIdx.x >> 6, lane = threadIdx.x & 63;
  int g = lane >> 4, gl = lane & 15;
  for (int a = w; a < m; a += 4) {
    int i = members[c * MAXM + a];
    const float4* pi = reinterpret_cast<const float4*>(emb + (size_t)i * DIM + gl * 8);
    float4 xi0 = pi[0], xi1 = pi[1];
    float ni = norms[i];
    float best = 0.f;
    for (int b = g; b < m; b += 4) {
      if (b == a) continue;
      int j = members[c * MAXM + b];
      const float4* pj = reinterpret_cast<const float4*>(emb + (size_t)j * DIM + gl * 8);
      float4 xj0 = pj[0], xj1 = pj[1];
      float d = xi0.x*xj0.x + xi0.y*xj0.y + xi0.z*xj0.z + xi0.w*xj0.w
              + xi1.x*xj1.x + xi1.y*xj1.y + xi1.z*xj1.z + xi1.w*xj1.w;
      #pragma unroll
      for (int off = 1; off < 16; off <<= 1) d += __shfl_xor(d, off);
      float sq = fmaxf(ni + norms[j] - 2.f * d, 0.f);
      best = fmaxf(best, sq);
    }
    best = fmaxf(best, __shfl_xor(best, 16));
    best = fmaxf(best, __shfl_xor(best, 32));
    if (lane == 0) hp[i] = best > 0.f ? sqrtf(best) : 0.f;
  }
}

// ---------- k_main: symmetric-triangle 128x128 tile, row+col passes ----------
// block (pi,pj), pj>=pi. A = panel pi rows (regs, full K); B = panel pj cols
// staged in K-quarters (16KB, dbuf, kg-major layout, conflict-free ds_read).
// Row-pass: t = 2dot - nj, running max -> rowres[row of pi][slot pj].
// Col-pass (pi!=pj): t_col = 2dot - ni -> rowres[col of pj][slot pi].
__global__ __launch_bounds__(256, 2) void k_main(
    const _Float16* __restrict__ eh, const _Float16* __restrict__ el,
    const int* __restrict__ labels, const float* __restrict__ norms,
    const float* __restrict__ hp, float* __restrict__ rowres) {
  int idx = blockIdx.x;
  int bx = (int)((sqrtf(8.0f * (float)idx + 1.0f) - 1.0f) * 0.5f);
  while ((bx + 1) * (bx + 2) / 2 <= idx) ++bx;
  while (bx * (bx + 1) / 2 > idx) --bx;
  const int pi = idx - bx * (bx + 1) / 2;   // row panel
  const int pj = bx;                        // col panel (pj >= pi)
  const int i0 = pi * 128, j0 = pj * 128;

  __shared__ __align__(16) char lds[32768];
  const int t = threadIdx.x, lane = t & 63, w = t >> 6;
  const int r16 = lane & 15, kg = lane >> 4;

  // stage one K-quarter (k = kq*32..+32) of B panel (h+l, 16KB) into buf C.
  // LDS 16B-unit layout: hl*512 + kslot*128 + col ; linear dest, per-lane src.
  #define STAGE(KQ, C)                                                        \
    {                                                                         \
      _Pragma("unroll") for (int it = 0; it < 4; ++it) {                      \
        const _Float16* sb = (it < 2) ? eh : el;                              \
        int kslot = (it * 2 + (t >> 7)) & 3;                                  \
        const _Float16* gp = sb + (size_t)(j0 + (t & 127)) * DIM              \
                             + (KQ) * 32 + kslot * 8;                         \
        char* lp = lds + (C) * 16384 + it * 4096 + (t >> 6) * 1024;           \
        __builtin_amdgcn_global_load_lds(                                     \
            (const __attribute__((address_space(1))) void*)gp,                \
            (__attribute__((address_space(3))) void*)lp, 16, 0, 0);           \
      }                                                                       \
    }

  // A fragments: rows i0 + 32w + 16m + r16, full K in quarters
  half8 ah[2][4], al[2][4];
  #pragma unroll
  for (int m = 0; m < 2; ++m) {
    size_t rbase = (size_t)(i0 + 32 * w + 16 * m + r16) * DIM + kg * 8;
    #pragma unroll
    for (int ks = 0; ks < 4; ++ks) {
      ah[m][ks] = *reinterpret_cast<const half8*>(eh + rbase + ks * 32);
      al[m][ks] = *reinterpret_cast<const half8*>(el + rbase + ks * 32);
    }
  }

  // row constants
  float ni_[2][4], c2[2][4], rmax[2][4], smax[2][4];
  int li[2][4];
  #pragma unroll
  for (int m = 0; m < 2; ++m)
    #pragma unroll
    for (int q = 0; q < 4; ++q) {
      int gi = i0 + 32 * w + 16 * m + 4 * kg + q;
      float nv = norms[gi], h = hp[gi];
      ni_[m][q] = nv;
      c2[m][q]  = nv - h * h;
      li[m][q]  = labels[gi];
      rmax[m][q] = -BIGF;
      smax[m][q] = -BIGF;
    }
  // col constants
  float njv[8], c2j[8];
  int ljv[8];
  #pragma unroll
  for (int n = 0; n < 8; ++n) {
    int gj = j0 + 16 * n + r16;
    float nv = norms[gj], hj = hp[gj];
    njv[n] = nv;
    c2j[n] = nv - hj * hj;
    ljv[n] = labels[gj];
  }

  f32x4 acc[2][8];
  #pragma unroll
  for (int m = 0; m < 2; ++m)
    #pragma unroll
    for (int n = 0; n < 8; ++n) acc[m][n] = (f32x4){0.f, 0.f, 0.f, 0.f};

  STAGE(0, 0);
  __syncthreads();
  #pragma unroll
  for (int kq = 0; kq < 4; ++kq) {
    if (kq < 3) STAGE(kq + 1, (kq + 1) & 1);
    __builtin_amdgcn_s_setprio(1);
    #pragma unroll
    for (int n = 0; n < 8; ++n) {
      const char* pb = lds + (kq & 1) * 16384 + kg * 2048 + (16 * n + r16) * 16;
      half8 bh = *reinterpret_cast<const half8*>(pb);
      half8 bl = *reinterpret_cast<const half8*>(pb + 8192);
      #pragma unroll
      for (int m = 0; m < 2; ++m) {
        acc[m][n] = __builtin_amdgcn_mfma_f32_16x16x32_f16(ah[m][kq], bh, acc[m][n], 0, 0, 0);
        acc[m][n] = __builtin_amdgcn_mfma_f32_16x16x32_f16(al[m][kq], bh, acc[m][n], 0, 0, 0);
        acc[m][n] = __builtin_amdgcn_mfma_f32_16x16x32_f16(ah[m][kq], bl, acc[m][n], 0, 0, 0);
      }
    }
    __builtin_amdgcn_s_setprio(0);
    if (kq < 3) __syncthreads();
  }
  #undef STAGE

  // ---- epilogue: row + col masked running max in t-space ----
  // C/D layout: col = r16, row = 4*kg + reg(q)
  float crmax[8], csmax[8];
  #pragma unroll
  for (int n = 0; n < 8; ++n) { crmax[n] = -BIGF; csmax[n] = -BIGF; }
  #pragma unroll
  for (int m = 0; m < 2; ++m)
    #pragma unroll
    for (int q = 0; q < 4; ++q)
      #pragma unroll
      for (int n = 0; n < 8; ++n) {
        float d2 = acc[m][n][q] + acc[m][n][q];
        bool diff = (li[m][q] != ljv[n]);
        float tr = d2 - njv[n];
        float trm = diff ? tr : -BIGF;
        rmax[m][q] = fmaxf(rmax[m][q], trm);
        smax[m][q] = fmaxf(smax[m][q], (trm < c2[m][q]) ? trm : -BIGF);
        float tc = d2 - ni_[m][q];
        float tcm = diff ? tc : -BIGF;
        crmax[n] = fmaxf(crmax[n], tcm);
        csmax[n] = fmaxf(csmax[n], (tcm < c2j[n]) ? tcm : -BIGF);
      }

  float2* pp = reinterpret_cast<float2*>(rowres);
  // row pass: reduce over the 16 col-lanes (r16), write slot pj
  #pragma unroll
  for (int m = 0; m < 2; ++m)
    #pragma unroll
    for (int q = 0; q < 4; ++q) {
      float r = rmax[m][q], s = smax[m][q];
      #pragma unroll
      for (int off = 1; off < 16; off <<= 1) {
        r = fmaxf(r, __shfl_xor(r, off));
        s = fmaxf(s, __shfl_xor(s, off));
      }
      if (r16 == 0) {
        int gi = i0 + 32 * w + 16 * m + 4 * kg + q;
        pp[(size_t)gi * NSLOT + pj] = make_float2(r, s);
      }
    }
  // col pass: reduce over kg lanes, write slot pi (skip diagonal)
  if (pi != pj) {
    #pragma unroll
    for (int n = 0; n < 8; ++n) {
      float r = crmax[n], s = csmax[n];
      r = fmaxf(r, __shfl_xor(r, 16));
      s = fmaxf(s, __shfl_xor(s, 16));
      r = fmaxf(r, __shfl_xor(r, 32));
      s = fmaxf(s, __shfl_xor(s, 32));
      if (kg == 0) {
        int gj = j0 + 16 * n + r16;
        // NOTE: each wave covers only rows 32w..32w+31 of pi, so 4 waves
        // produce 4 partial col-maxes; combine via per-wave slot then max in
        // k_red would need 4 slots. Instead: stagger slots by wave and let
        // k_red's 64-slot max absorb it -- but slots are unique per block.
        // Resolve: reduce across waves through LDS (reuse staging buffer).
        reinterpret_cast<float2*>(lds)[(w * 8 + n) * 16 + r16] = make_float2(r, s);
      }
    }
    __syncthreads();
    // wave 0 merges the 4 per-wave col partials and writes
    if (w == 0) {
      #pragma unroll
      for (int n = 0; n < 8; ++n) {
        if (kg == 0) {
          float2 v0 = reinterpret_cast<float2*>(lds)[(0 * 8 + n) * 16 + r16];
          float2 v1 = reinterpret_cast<float2*>(lds)[(1 * 8 + n) * 16 + r16];
          float2 v2 = reinterpret_cast<float2*>(lds)[(2 * 8 + n) * 16 + r16];
          float2 v3 = reinterpret_cast<float2*>(lds)[(3 * 8 + n) * 16 + r16];
          float r = fmaxf(fmaxf(v0.x, v1.x), fmaxf(v2.x, v3.x));
          float s = fmaxf(fmaxf(v0.y, v1.y), fmaxf(v2.y, v3.y));
          int gj = j0 + 16 * n + r16;
          pp[(size_t)gj * NSLOT + pi] = make_float2(r, s);
        }
      }
    }
  }
}

// ---------- k_red: per-row combine of 64 slots -> per-block partial ----------
__global__ __launch_bounds__(256) void k_red(
    const float* __restrict__ norms, const float* __restrict__ hp,
    const float* __restrict__ rowres, float* __restrict__ partial) {
  int gt = blockIdx.x * 256 + threadIdx.x;   // 32768 threads, 4 per row
  int row = gt >> 2, q = gt & 3;
  const float2* pp = reinterpret_cast<const float2*>(rowres) + (size_t)row * NSLOT + q * 16;
  float rmax = -BIGF, smax = -BIGF;
  #pragma unroll
  for (int s = 0; s < 16; ++s) {
    float2 v = pp[s];
    rmax = fmaxf(rmax, v.x);
    smax = fmaxf(smax, v.y);
  }
  rmax = fmaxf(rmax, __shfl_xor(rmax, 1));
  smax = fmaxf(smax, __shfl_xor(smax, 1));
  rmax = fmaxf(rmax, __shfl_xor(rmax, 2));
  smax = fmaxf(smax, __shfl_xor(smax, 2));
  float total = 0.f, count = 0.f;
  if (q == 0) {
    float ni = norms[row], h = hp[row];
    float c1 = ni - (h + TMARGIN) * (h + TMARGIN);
    bool has_neg = rmax > -1e37f;
    float neg_sq  = fmaxf(ni - rmax, 0.f);
    float semi_sq = (smax > c1) ? fmaxf(ni - smax, 0.f) : neg_sq;
    if (h > 0.f && has_neg) {
      total = fmaxf(h - sqrtf(semi_sq) + TMARGIN, 0.f);
      count = 1.f;
    }
  }
  #pragma unroll
  for (int off = 32; off; off >>= 1) {
    total += __shfl_xor(total, off);
    count += __shfl_xor(count, off);
  }
  __shared__ float st[4], sc[4];
  int w = threadIdx.x >> 6, lane = threadIdx.x & 63;
  if (lane == 0) { st[w] = total; sc[w] = count; }
  __syncthreads();
  if (threadIdx.x == 0) {
    float2* po = reinterpret_cast<float2*>(partial);
    po[blockIdx.x] = make_float2(st[0] + st[1] + st[2] + st[3],
                                 sc[0] + sc[1] + sc[2] + sc[3]);
  }
}

// ---------- k_out: final scalar ----------------------------------------------
__global__ void k_out(const float* __restrict__ partial, float* __restrict__ out) {
  const float2* pp = reinterpret_cast<const float2*>(partial);
  int lane = threadIdx.x;
  float2 a = pp[lane], b = pp[lane + 64];
  float T = a.x + b.x, C = a.y + b.y;
  #pragma unroll
  for (int off = 32; off; off >>= 1) {
    T += __shfl_xor(T, off);
    C += __shfl_xor(C, off);
  }
  if (lane == 0) out[0] = C > 0.f ? T / C : 0.f;
}

extern "C" void kernel_launch(void* const* d_in, const int* in_sizes, int n_in,
                              void* d_out, int out_size, void* d_ws, size_t ws_size,
                              hipStream_t stream) {
  const float* emb  = (const float*)d_in[0];
  const int* labels = (const int*)d_in[1];
  float* out        = (float*)d_out;

  _Float16* eh  = (_Float16*)d_ws;                     // 2 MB
  _Float16* el  = eh + (size_t)BATCH * DIM;            // 2 MB
  float* norms  = (float*)(el + (size_t)BATCH * DIM);  // 32 KB
  float* hp     = norms + BATCH;                       // 32 KB
  int* counts   = (int*)(hp + BATCH);                  // 2 KB
  int* members  = counts + NCLS;                       // 256 KB
  float* rowres = (float*)(members + NCLS * MAXM);     // 4 MB
  float* partial = rowres + (size_t)BATCH * NSLOT * 2; // 1 KB

  hipMemsetAsync(counts, 0, NCLS * sizeof(int), stream);
  k_prep<<<BATCH / 4, 256, 0, stream>>>(emb, labels, eh, el, norms, counts, members);
  k_hp<<<NCLS, 256, 0, stream>>>(emb, norms, counts, members, hp);
  const int ntri = NPAN * (NPAN + 1) / 2;   // 2080
  k_main<<<ntri, 256, 0, stream>>>(eh, el, labels, norms, hp, rowres);
  k_red<<<BATCH * 4 / 256, 256, 0, stream>>>(norms, hp, rowres, partial);
  k_out<<<1, 64, 0, stream>>>(partial, out);
}